// Round 20
// baseline (237.380 us; speedup 1.0000x reference)
//
#include <hip/hip_runtime.h>

#define HH 1024
#define VV 32000
#define LL 15
#define BB 512

typedef __bf16 bf16;
typedef __bf16 bf16x4 __attribute__((ext_vector_type(4)));
typedef __bf16 bf16x8 __attribute__((ext_vector_type(8)));
typedef float f32x4 __attribute__((ext_vector_type(4)));

#define VMCNT(n) asm volatile("s_waitcnt vmcnt(" #n ")" ::: "memory")
#define SBAR     __builtin_amdgcn_s_barrier()
#define SCHED0   __builtin_amdgcn_sched_barrier(0)

__device__ __forceinline__ unsigned short f2bf(float f) {
    unsigned int u = __float_as_uint(f);
    unsigned int r = (u + 0x7fffu + ((u >> 16) & 1u)) >> 16;  // RNE
    return (unsigned short)r;
}
__device__ __forceinline__ float bf2f(unsigned short u) {
    return __uint_as_float(((unsigned int)u) << 16);
}

__device__ __forceinline__ void gld_lds16(const void* g, void* l) {
    __builtin_amdgcn_global_load_lds(
        (const __attribute__((address_space(1))) unsigned int*)g,
        (__attribute__((address_space(3))) unsigned int*)l, 16, 0, 0);
}

// ---------------------------------------------------------------------------
// cvt_kernel: w_ih/w_hh/combine_w/hidden f32->bf16 (2048 float8 units/block).
// ---------------------------------------------------------------------------
#define CVT0   (3 * HH * HH / 8)                // 393,216
#define CVT1   (3 * HH * HH / 8)                // 393,216
#define CVT2   (2 * HH * HH / 8)                // 262,144
#define NCVTB  544

__global__ __launch_bounds__(256)
void cvt_kernel(const float* __restrict__ w_ih, unsigned short* __restrict__ w_ih_bf,
                const float* __restrict__ w_hh, unsigned short* __restrict__ w_hh_bf,
                const float* __restrict__ combine_w, unsigned short* __restrict__ w_cb_bf,
                const float* __restrict__ hidden, unsigned short* __restrict__ hid_bf) {
    int ub = blockIdx.x * 2048 + threadIdx.x;
    const float* src; unsigned short* dst;
    if (ub < CVT0) { src = w_ih; dst = w_ih_bf; }
    else if ((ub -= CVT0) < CVT1) { src = w_hh; dst = w_hh_bf; }
    else if ((ub -= CVT1) < CVT2) { src = combine_w; dst = w_cb_bf; }
    else { ub -= CVT2; src = hidden; dst = hid_bf; }

    #pragma unroll
    for (int q = 0; q < 8; q++) {
        const int i = ub + q * 256;
        const f32x4 a = ((const f32x4*)src)[2 * i];
        const f32x4 b = ((const f32x4*)src)[2 * i + 1];
        const bf16x4 wa = __builtin_convertvector(a, bf16x4);
        const bf16x4 wb = __builtin_convertvector(b, bf16x4);
        bf16x8 w;
        #pragma unroll
        for (int c = 0; c < 4; c++) { w[c] = wa[c]; w[c + 4] = wb[c]; }
        *(bf16x8*)&dst[(size_t)i * 8] = w;
    }
}

// ---------------------------------------------------------------------------
// Attention (r2-proven standalone): stage enc[.,b,:] (60 KB) in LDS.
// ---------------------------------------------------------------------------
__global__ __launch_bounds__(256)
void attn_kernel(const int* __restrict__ ids, const float* __restrict__ enc,
                 const float* __restrict__ embedding,
                 const float* __restrict__ attn1_w, const float* __restrict__ attn1_b,
                 float* __restrict__ attn_out, unsigned short* __restrict__ cat_out) {
    const int b = blockIdx.x, tid = threadIdx.x;
    const int lane = tid & 63, wv = tid >> 6;

    __shared__ float s_enc[LL * HH];
    __shared__ float s_scores[LL];
    __shared__ float s_red[4];

    for (int idx = tid; idx < LL * HH / 4; idx += 256) {
        const int l = (idx * 4) >> 10, h = (idx * 4) & (HH - 1);
        *(f32x4*)&s_enc[idx * 4] = *(const f32x4*)&enc[((size_t)l * BB + b) * HH + h];
    }

    const float* embr = embedding + (size_t)ids[b] * HH;
    float p = 0.f;
    for (int j = tid; j < HH; j += 256) p += embr[j] * attn1_w[j];
    #pragma unroll
    for (int o = 32; o; o >>= 1) p += __shfl_xor(p, o);
    if (lane == 0) s_red[wv] = p;
    __syncthreads();
    const float semb = s_red[0] + s_red[1] + s_red[2] + s_red[3] + attn1_b[0];

    for (int l = wv; l < LL; l += 4) {
        float q = 0.f;
        for (int j = lane; j < HH; j += 64) q += s_enc[l * HH + j] * attn1_w[HH + j];
        #pragma unroll
        for (int o = 32; o; o >>= 1) q += __shfl_xor(q, o);
        if (lane == 0) s_scores[l] = q + semb;
    }
    __syncthreads();

    float mx = -3.4e38f;
    #pragma unroll
    for (int l = 0; l < LL; l++) mx = fmaxf(mx, s_scores[l]);
    float aw[LL], sum = 0.f;
    #pragma unroll
    for (int l = 0; l < LL; l++) { aw[l] = __expf(s_scores[l] - mx); sum += aw[l]; }
    const float inv = 1.f / sum;
    #pragma unroll
    for (int l = 0; l < LL; l++) aw[l] *= inv;

    if (tid < LL) attn_out[tid * BB + b] = aw[tid];

    for (int j = tid; j < HH; j += 256) {
        float c = 0.f;
        #pragma unroll
        for (int l = 0; l < LL; l++) c += aw[l] * s_enc[l * HH + j];
        cat_out[(size_t)b * (2 * HH) + j] = f2bf(embr[j]);
        cat_out[(size_t)b * (2 * HH) + HH + j] = f2bf(c);
    }
}

// ---------------------------------------------------------------------------
// bf16 NT GEMM, counted-vmcnt pipeline (r7/r11, replay-proven).
// GATES=1: blockIdx.z picks second operand set.
// ---------------------------------------------------------------------------
template<int TM, int TN, int OUT, int GATES>
__global__ __launch_bounds__(256)
void gemm_nt(const bf16* __restrict__ A, const bf16* __restrict__ B,
             const float* __restrict__ bias, void* __restrict__ Cout,
             const bf16* __restrict__ A2, const bf16* __restrict__ B2,
             const float* __restrict__ bias2, void* __restrict__ C2,
             const int K, const int N) {
    constexpr int FM = TM / 32, FN = TN / 32;
    __shared__ bf16 As[2][TM * 64];
    __shared__ bf16 Bs[2][TN * 64];

    if (GATES && blockIdx.z == 1) { A = A2; B = B2; bias = bias2; Cout = C2; }

    const int tid = threadIdx.x;
    const int lane = tid & 63, wave = tid >> 6;
    const int wm = wave >> 1, wn = wave & 1;
    const int rlo = lane & 15, khi = lane >> 4;
    const int m0 = blockIdx.y * TM, n0 = blockIdx.x * TN;

    f32x4 acc[FM][FN] = {};
    constexpr int IA = TM / 32, IB = TN / 32;

    auto stage = [&](int k0, int buf) {
        #pragma unroll
        for (int i = 0; i < IA; i++) {
            const int p = (i * 256 + tid) * 16;
            const int row = p >> 7;
            const int qs = (p & 127) ^ ((row & 7) << 4);
            gld_lds16(A + (size_t)(m0 + row) * K + k0 + (qs >> 1),
                      &As[buf][0] + i * 2048 + wave * 512);
        }
        #pragma unroll
        for (int i = 0; i < IB; i++) {
            const int p = (i * 256 + tid) * 16;
            const int row = p >> 7;
            const int qs = (p & 127) ^ ((row & 7) << 4);
            gld_lds16(B + (size_t)(n0 + row) * K + k0 + (qs >> 1),
                      &Bs[buf][0] + i * 2048 + wave * 512);
        }
    };

    auto compute = [&](int buf) {
        #pragma unroll
        for (int ks = 0; ks < 2; ks++) {
            bf16x8 af[FM], bfr[FN];
            #pragma unroll
            for (int m = 0; m < FM; m++) {
                const int r = wm * (TM / 2) + m * 16 + rlo;
                const int sw = (ks * 64 + khi * 16) ^ ((r & 7) << 4);
                af[m] = *(const bf16x8*)((const char*)&As[buf][0] + r * 128 + sw);
            }
            #pragma unroll
            for (int n = 0; n < FN; n++) {
                const int r = wn * (TN / 2) + n * 16 + rlo;
                const int sw = (ks * 64 + khi * 16) ^ ((r & 7) << 4);
                bfr[n] = *(const bf16x8*)((const char*)&Bs[buf][0] + r * 128 + sw);
            }
            #pragma unroll
            for (int m = 0; m < FM; m++)
                #pragma unroll
                for (int n = 0; n < FN; n++)
                    acc[m][n] = __builtin_amdgcn_mfma_f32_16x16x32_bf16(af[m], bfr[n], acc[m][n], 0, 0, 0);
        }
    };

    const int NT = K >> 6;
    stage(0, 0);
    stage(64, 1);

    for (int kt = 0; kt < NT; kt += 2) {
        {
            const int t = kt;
            if (t + 1 < NT) { VMCNT(4); } else { VMCNT(0); }
            SCHED0; SBAR; SCHED0;
            compute(0);
            SCHED0; SBAR; SCHED0;
            if (t + 2 < NT) stage((t + 2) << 6, 0);
        }
        {
            const int t = kt + 1;
            if (t + 1 < NT) { VMCNT(4); } else { VMCNT(0); }
            SCHED0; SBAR; SCHED0;
            compute(1);
            SCHED0; SBAR; SCHED0;
            if (t + 2 < NT) stage((t + 2) << 6, 1);
        }
    }

    #pragma unroll
    for (int m = 0; m < FM; m++) {
        const int gr = m0 + wm * (TM / 2) + m * 16 + khi * 4;
        #pragma unroll
        for (int n = 0; n < FN; n++) {
            const int gc = n0 + wn * (TN / 2) + n * 16 + rlo;
            const float bv = bias[gc];
            #pragma unroll
            for (int j = 0; j < 4; j++) {
                float v = acc[m][n][j] + bv;
                if (OUT == 1) {
                    v = fmaxf(v, 0.f);
                    ((unsigned short*)Cout)[(size_t)(gr + j) * N + gc] = f2bf(v);
                } else {
                    ((float*)Cout)[(size_t)(gr + j) * N + gc] = v;
                }
            }
        }
    }
}

// ---------------------------------------------------------------------------
// Logits GEMM, NO PACK: B = out_w f32 read directly in 1-KB row chunks.
// TM=256 x TN=64, 512 thr (8 waves = 4m x 2n; wave = 64m x 32n).
// Per K-tile (256): stage 64 rows x 1KB f32 -> 64KB LDS via gld_lds
// (pre-swizzled source, XOR ((r&7)<<5) on 16B slots); then 4 k-steps of
// compute: A bf16 frags from global (L2-hot), B from LDS (f32->bf16 at
// frag load). 64KB LDS -> 2 blocks/CU phase overlap.
// FIX vs r19: Arow must NOT pre-add khi*8 (koff already includes it).
// CB=0: C f32; CB=1: C bf16 -> Cb. Per-row (max,sumexp) partials.
// ---------------------------------------------------------------------------
template<int CB>
__global__ __launch_bounds__(512, 2)
void gemm_direct(const bf16* __restrict__ A, const float* __restrict__ B,
                 const float* __restrict__ bias, float* __restrict__ C,
                 unsigned short* __restrict__ Cb,
                 float* __restrict__ pmax, float* __restrict__ psum) {
    constexpr int K = HH, N = VV;
    __shared__ __align__(16) float Bsf[64 * 256];   // 64 KB, one K-tile of B
    __shared__ float sPm[2][256], sPs[2][256];

    const int tid = threadIdx.x;
    const int lane = tid & 63, wave = tid >> 6;      // 8 waves
    const int wm = wave >> 1, wn = wave & 1;          // 4m x 2n
    const int rlo = lane & 15, khi = lane >> 4;

    // XCD swizzle: 500 n-panels x 2 m-blocks; chunk 16 = 2jm x 8g so panel
    // siblings (rem, rem+8) are 8 apart -> same XCD in round-robin.
    constexpr int gridN = 500;
    constexpr int nFull = (gridN >> 3) << 4;          // 992
    const int bidx = blockIdx.x;
    int g, jm;
    if (bidx < nFull) { const int s = bidx >> 4, rem = bidx & 15; jm = rem >> 3; g = s * 8 + (rem & 7); }
    else { const int rem = bidx - nFull; g = 496 + (rem & 3); jm = rem >> 2; }
    const int n0 = g * 64, m0 = jm * 256;

    f32x4 acc[4][2] = {};

    const bf16* Arow = A + (size_t)(m0 + wm * 64 + rlo) * K;   // khi*8 lives in koff

    for (int t = 0; t < 4; t++) {                     // K-tiles of 256
        // stage: 64 rows x 1KB f32, pre-swizzled source, linear LDS dest
        #pragma unroll
        for (int i = 0; i < 8; i++) {
            const int r = i * 8 + wave;
            const int cb = (lane * 16) ^ ((r & 7) << 5);   // swizzled col bytes
            gld_lds16(B + (size_t)(n0 + r) * K + t * 256 + (cb >> 2),
                      (char*)Bsf + r * 1024);
        }
        VMCNT(0);
        SCHED0; SBAR; SCHED0;

        // 4 k-steps of 64 (B from LDS, A from global/L2)
        #pragma unroll
        for (int kstep = 0; kstep < 4; kstep++) {
            #pragma unroll
            for (int ks = 0; ks < 2; ks++) {
                const int koff = kstep * 64 + ks * 32 + khi * 8;   // f32/bf16 k idx
                bf16x8 af[4], bfr[2];
                #pragma unroll
                for (int m = 0; m < 4; m++)
                    af[m] = *(const bf16x8*)(Arow + (size_t)m * 16 * K + t * 256 + koff);
                #pragma unroll
                for (int n = 0; n < 2; n++) {
                    const int r = wn * 32 + n * 16 + rlo;
                    const char* p = (const char*)Bsf + r * 1024 + ((koff * 4) ^ ((r & 7) << 5));
                    const f32x4 lo = *(const f32x4*)p;
                    const f32x4 hi = *(const f32x4*)(p + 16);
                    const bf16x4 wa = __builtin_convertvector(lo, bf16x4);
                    const bf16x4 wb = __builtin_convertvector(hi, bf16x4);
                    bf16x8 w;
                    #pragma unroll
                    for (int c = 0; c < 4; c++) { w[c] = wa[c]; w[c + 4] = wb[c]; }
                    bfr[n] = w;
                }
                #pragma unroll
                for (int m = 0; m < 4; m++)
                    #pragma unroll
                    for (int n = 0; n < 2; n++)
                        acc[m][n] = __builtin_amdgcn_mfma_f32_16x16x32_bf16(af[m], bfr[n], acc[m][n], 0, 0, 0);
            }
        }
        SCHED0; SBAR; SCHED0;                         // LDS reads done before restage
    }

    // epilogue: C store + per-row (max,sumexp) partials over this wave's 32 cols
    float bvn[2];
    #pragma unroll
    for (int n = 0; n < 2; n++) bvn[n] = bias[n0 + wn * 32 + n * 16 + rlo];

    #pragma unroll
    for (int m = 0; m < 4; m++) {
        const int rbase = wm * 64 + m * 16 + khi * 4;
        #pragma unroll
        for (int j = 0; j < 4; j++) {
            const int gr = m0 + rbase + j;
            float v[2];
            #pragma unroll
            for (int n = 0; n < 2; n++) {
                v[n] = acc[m][n][j] + bvn[n];
                const size_t ci = (size_t)gr * N + n0 + wn * 32 + n * 16 + rlo;
                if (CB) Cb[ci] = f2bf(v[n]); else C[ci] = v[n];
            }
            float lm = fmaxf(v[0], v[1]);
            #pragma unroll
            for (int o = 8; o; o >>= 1) lm = fmaxf(lm, __shfl_xor(lm, o));
            float ls = __expf(v[0] - lm) + __expf(v[1] - lm);
            #pragma unroll
            for (int o = 8; o; o >>= 1) ls += __shfl_xor(ls, o);
            if (rlo == 0) { sPm[wn][rbase + j] = lm; sPs[wn][rbase + j] = ls; }
        }
    }
    __syncthreads();
    if (tid < 256) {
        const float ma = sPm[0][tid], mb = sPm[1][tid];
        const float M = fmaxf(ma, mb);
        const float S = sPs[0][tid] * __expf(ma - M) + sPs[1][tid] * __expf(mb - M);
        pmax[(size_t)(m0 + tid) * 512 + g] = M;
        psum[(size_t)(m0 + tid) * 512 + g] = S;
    }
}

// ---------------------------------------------------------------------------
// GRU gates (x4 vectorized); writes h_new f32 (output) + bf16 (A operand)
// ---------------------------------------------------------------------------
__global__ __launch_bounds__(256)
void gru_kernel(const float* __restrict__ gi, const float* __restrict__ gh,
                const float* __restrict__ h, float* __restrict__ hnew,
                unsigned short* __restrict__ hnew_bf) {
    const int i = blockIdx.x * 256 + threadIdx.x;        // x4 elems
    const int e = i * 4;
    const int b = e >> 10, j = e & (HH - 1);
    const size_t o = ((size_t)b * 3 * HH + j) / 4;       // f32x4 units
    const f32x4 ir = ((const f32x4*)gi)[o],          iz = ((const f32x4*)gi)[o + HH / 4],
                in_ = ((const f32x4*)gi)[o + 2 * HH / 4];
    const f32x4 hr = ((const f32x4*)gh)[o],          hz = ((const f32x4*)gh)[o + HH / 4],
                hn = ((const f32x4*)gh)[o + 2 * HH / 4];
    const f32x4 hv = ((const f32x4*)h)[i];
    f32x4 out;
    ushort4 ob;
    #pragma unroll
    for (int c = 0; c < 4; c++) {
        const float r = 1.f / (1.f + __expf(-(ir[c] + hr[c])));
        const float z = 1.f / (1.f + __expf(-(iz[c] + hz[c])));
        const float n = tanhf(in_[c] + r * hn[c]);
        const float v = (1.f - z) * n + z * hv[c];
        out[c] = v;
        ((unsigned short*)&ob)[c] = f2bf(v);
    }
    ((f32x4*)hnew)[i] = out;
    ((ushort4*)hnew_bf)[i] = ob;
}

// ---------------------------------------------------------------------------
// log-softmax finalize: combine 500 partials -> lse, subtract.
// CB=0: in-place f32. CB=1: read bf16 Cb, write f32.
// ---------------------------------------------------------------------------
template<int CB>
__global__ __launch_bounds__(512)
void lsm_final(const float* __restrict__ pmax, const float* __restrict__ psum,
               const unsigned short* __restrict__ Cb, float* __restrict__ logits) {
    const int b = blockIdx.x, tid = threadIdx.x;
    const int lane = tid & 63, wv = tid >> 6;
    __shared__ float sm[8], ss[8];

    float m = -3.4e38f, s = 0.f;
    if (tid < 500) { m = pmax[(size_t)b * 512 + tid]; s = psum[(size_t)b * 512 + tid]; }
    #pragma unroll
    for (int o = 32; o; o >>= 1) {
        const float mo = __shfl_xor(m, o), so = __shfl_xor(s, o);
        const float nm = fmaxf(m, mo);
        s = s * __expf(m - nm) + so * __expf(mo - nm);
        m = nm;
    }
    if (lane == 0) { sm[wv] = m; ss[wv] = s; }
    __syncthreads();
    float M = sm[0], S;
    #pragma unroll
    for (int w = 1; w < 8; w++) M = fmaxf(M, sm[w]);
    S = ss[0] * __expf(sm[0] - M);
    #pragma unroll
    for (int w = 1; w < 8; w++) S += ss[w] * __expf(sm[w] - M);
    const float lse = M + __logf(S);

    float* row = logits + (size_t)b * VV;
    if (CB) {
        const unsigned short* rowc = Cb + (size_t)b * VV;
        for (int j = tid; j < VV / 8; j += 512) {
            const ushort4 u0 = ((const ushort4*)rowc)[2 * j];
            const ushort4 u1 = ((const ushort4*)rowc)[2 * j + 1];
            f32x4 v0, v1;
            v0[0] = bf2f(u0.x) - lse; v0[1] = bf2f(u0.y) - lse;
            v0[2] = bf2f(u0.z) - lse; v0[3] = bf2f(u0.w) - lse;
            v1[0] = bf2f(u1.x) - lse; v1[1] = bf2f(u1.y) - lse;
            v1[2] = bf2f(u1.z) - lse; v1[3] = bf2f(u1.w) - lse;
            ((f32x4*)row)[2 * j] = v0;
            ((f32x4*)row)[2 * j + 1] = v1;
        }
    } else {
        for (int j = tid; j < VV / 4; j += 512) {
            f32x4 v = ((const f32x4*)row)[j];
            v[0] -= lse; v[1] -= lse; v[2] -= lse; v[3] -= lse;
            ((f32x4*)row)[j] = v;
        }
    }
}

// ---------------------------------------------------------------------------
extern "C" void kernel_launch(void* const* d_in, const int* in_sizes, int n_in,
                              void* d_out, int out_size, void* d_ws, size_t ws_size,
                              hipStream_t stream) {
    const int*   ids       = (const int*)d_in[0];
    const float* hidden    = (const float*)d_in[1];
    const float* enc       = (const float*)d_in[2];
    const float* embedding = (const float*)d_in[4];
    const float* attn1_w   = (const float*)d_in[5];
    const float* attn1_b   = (const float*)d_in[6];
    const float* combine_w = (const float*)d_in[7];
    const float* combine_b = (const float*)d_in[8];
    const float* w_ih      = (const float*)d_in[9];
    const float* w_hh      = (const float*)d_in[10];
    const float* b_ih      = (const float*)d_in[11];
    const float* b_hh      = (const float*)d_in[12];
    const float* out_w     = (const float*)d_in[13];
    const float* out_b     = (const float*)d_in[14];

    float* out_lsm = (float*)d_out;                  // [B,V]
    float* out_h   = out_lsm + (size_t)BB * VV;      // [1,B,H]
    float* out_aw  = out_h + (size_t)BB * HH;        // [L,B,1]

    // ws layout: each buffer has exactly one writer kernel; no overlays.
    char* w = (char*)d_ws;
    unsigned short* w_ih_bf  = (unsigned short*)w;   w += (size_t)3 * HH * HH * 2;
    unsigned short* w_hh_bf  = (unsigned short*)w;   w += (size_t)3 * HH * HH * 2;
    unsigned short* w_cb_bf  = (unsigned short*)w;   w += (size_t)2 * HH * HH * 2;
    unsigned short* cat_bf   = (unsigned short*)w;   w += (size_t)BB * 2 * HH * 2;
    unsigned short* x_bf     = (unsigned short*)w;   w += (size_t)BB * HH * 2;
    unsigned short* hid_bf   = (unsigned short*)w;   w += (size_t)BB * HH * 2;
    unsigned short* hnew_bf  = (unsigned short*)w;   w += (size_t)BB * HH * 2;
    float* gi   = (float*)w;                         w += (size_t)BB * 3 * HH * 4;
    float* gh   = (float*)w;                         w += (size_t)BB * 3 * HH * 4;
    float* pmax = (float*)w;                         w += (size_t)BB * 512 * 4;
    float* psum = (float*)w;                         w += (size_t)BB * 512 * 4;
    unsigned short* Cb = (unsigned short*)w;         // optional, 32.77 MB, single writer
    const size_t needed_cb = (size_t)(w - (char*)d_ws) + (size_t)BB * VV * 2;
    const bool use_cb = ws_size >= needed_cb;        // deterministic per deployment

    // 1) weight/activation converts (no pack)
    cvt_kernel<<<NCVTB, 256, 0, stream>>>(
        w_ih, w_ih_bf, w_hh, w_hh_bf, combine_w, w_cb_bf, hidden, hid_bf);

    // 2) attention
    attn_kernel<<<BB, 256, 0, stream>>>(ids, enc, embedding, attn1_w, attn1_b, out_aw, cat_bf);

    // 3) x = relu(cat @ combine_w^T + b)   M=512 N=1024 K=2048 -> bf16
    gemm_nt<64, 64, 1, 0><<<dim3(HH / 64, BB / 64), 256, 0, stream>>>(
        (const bf16*)cat_bf, (const bf16*)w_cb_bf, combine_b, x_bf,
        nullptr, nullptr, nullptr, nullptr, 2 * HH, HH);

    // 4) z=0: gh = hidden @ w_hh^T ; z=1: gi = x @ w_ih^T   M=512 N=3072 K=1024
    gemm_nt<64, 64, 0, 1><<<dim3(3 * HH / 64, BB / 64, 2), 256, 0, stream>>>(
        (const bf16*)hid_bf, (const bf16*)w_hh_bf, b_hh, gh,
        (const bf16*)x_bf, (const bf16*)w_ih_bf, b_ih, gi, HH, 3 * HH);

    // 5) GRU gates
    gru_kernel<<<(BB * HH / 4) / 256, 256, 0, stream>>>(gi, gh, hidden, out_h, hnew_bf);

    // 6) logits (direct f32 B) + lsm partials; 7) lsm finalize
    if (use_cb) {
        gemm_direct<1><<<1000, 512, 0, stream>>>(
            (const bf16*)hnew_bf, out_w, out_b, nullptr, Cb, pmax, psum);
        lsm_final<1><<<BB, 512, 0, stream>>>(pmax, psum, Cb, out_lsm);
    } else {
        gemm_direct<0><<<1000, 512, 0, stream>>>(
            (const bf16*)hnew_bf, out_w, out_b, out_lsm, nullptr, pmax, psum);
        lsm_final<0><<<BB, 512, 0, stream>>>(pmax, psum, nullptr, out_lsm);
    }
}

// Round 21
// 171.868 us; speedup vs baseline: 1.3812x; 1.3812x over previous
//
#include <hip/hip_runtime.h>

#define HH 1024
#define VV 32000
#define LL 15
#define BB 512

typedef __bf16 bf16;
typedef __bf16 bf16x4 __attribute__((ext_vector_type(4)));
typedef __bf16 bf16x8 __attribute__((ext_vector_type(8)));
typedef float f32x4 __attribute__((ext_vector_type(4)));

#define VMCNT(n) asm volatile("s_waitcnt vmcnt(" #n ")" ::: "memory")
#define SBAR     __builtin_amdgcn_s_barrier()
#define SCHED0   __builtin_amdgcn_sched_barrier(0)

__device__ __forceinline__ unsigned short f2bf(float f) {
    unsigned int u = __float_as_uint(f);
    unsigned int r = (u + 0x7fffu + ((u >> 16) & 1u)) >> 16;  // RNE
    return (unsigned short)r;
}
__device__ __forceinline__ float bf2f(unsigned short u) {
    return __uint_as_float(((unsigned int)u) << 16);
}

__device__ __forceinline__ void gld_lds16(const void* g, void* l) {
    __builtin_amdgcn_global_load_lds(
        (const __attribute__((address_space(1))) unsigned int*)g,
        (__attribute__((address_space(3))) unsigned int*)l, 16, 0, 0);
}

// ---------------------------------------------------------------------------
// Fused prologue: [0,2000) pack out_w (r11 layout); [2000,6352) cvt4;
// [6352,6864) attention. Independent block ranges run concurrently.
// pack dst: [250 panels][16 ktiles][128 rows][64 k] bf16, ktile = 16 KB.
// ---------------------------------------------------------------------------
#define NPACKB 2000
#define NCVTB  4352

__global__ __launch_bounds__(256)
void prologue(const float* __restrict__ out_w, unsigned short* __restrict__ packed,
              const float* __restrict__ w_ih, unsigned short* __restrict__ w_ih_bf,
              const float* __restrict__ w_hh, unsigned short* __restrict__ w_hh_bf,
              const float* __restrict__ combine_w, unsigned short* __restrict__ w_cb_bf,
              const float* __restrict__ hidden, unsigned short* __restrict__ hid_bf,
              const int* __restrict__ ids, const float* __restrict__ enc,
              const float* __restrict__ embedding,
              const float* __restrict__ attn1_w, const float* __restrict__ attn1_b,
              float* __restrict__ attn_out, unsigned short* __restrict__ cat_out) {
    __shared__ float s_enc[LL * HH];
    __shared__ float s_scores[LL];
    __shared__ float s_red[4];

    const int bid = blockIdx.x, tid = threadIdx.x;

    if (bid < NPACKB) {
        // ---- pack out_w (r11-proven): 16-row strip, sequential 64 KB read
        const int g = bid >> 3, rq = bid & 7;               // 250 panels x 8 strips
        const float* s0 = out_w + ((size_t)g * 128 + rq * 16) * 1024;
        unsigned short* d0 = packed + (size_t)g * (16 * 128 * 64);
        #pragma unroll
        for (int j = 0; j < 16; j++) {
            const int s4 = j * 256 + tid;                   // f32x4 unit in 16x1024
            const f32x4 v = ((const f32x4*)s0)[s4];
            const int sp = s4 * 4;
            const int rl = rq * 16 + (sp >> 10);
            const int k = sp & 1023;
            bf16x4 w = __builtin_convertvector(v, bf16x4);
            *(bf16x4*)&d0[(size_t)(k >> 6) * 8192 + rl * 64 + (k & 63)] = w;
        }
        return;
    }
    if (bid < NPACKB + NCVTB) {
        // ---- cvt4: w_ih, w_hh, combine_w, hidden
        int i = (bid - NPACKB) * 256 + tid;                 // float8 units
        const float* src; unsigned short* dst;
        const int n0_ = 3 * HH * HH / 8, n1_ = 3 * HH * HH / 8;
        const int n2_ = 2 * HH * HH / 8, n3_ = BB * HH / 8;
        if (i < n0_) { src = w_ih; dst = w_ih_bf; }
        else if ((i -= n0_) < n1_) { src = w_hh; dst = w_hh_bf; }
        else if ((i -= n1_) < n2_) { src = combine_w; dst = w_cb_bf; }
        else if ((i -= n2_) < n3_) { src = hidden; dst = hid_bf; }
        else return;
        const f32x4 a = ((const f32x4*)src)[2 * i], b = ((const f32x4*)src)[2 * i + 1];
        ((bf16x4*)dst)[2 * i]     = __builtin_convertvector(a, bf16x4);
        ((bf16x4*)dst)[2 * i + 1] = __builtin_convertvector(b, bf16x4);
        return;
    }

    // ---- attention for batch row b (r12-proven)
    const int b = bid - (NPACKB + NCVTB);
    const int lane = tid & 63, wv = tid >> 6;

    for (int idx = tid; idx < LL * HH / 4; idx += 256) {
        const int l = (idx * 4) >> 10, h = (idx * 4) & (HH - 1);
        *(f32x4*)&s_enc[idx * 4] = *(const f32x4*)&enc[((size_t)l * BB + b) * HH + h];
    }

    const float* embr = embedding + (size_t)ids[b] * HH;
    float p = 0.f;
    for (int j = tid; j < HH; j += 256) p += embr[j] * attn1_w[j];
    #pragma unroll
    for (int o = 32; o; o >>= 1) p += __shfl_xor(p, o);
    if (lane == 0) s_red[wv] = p;
    __syncthreads();
    const float semb = s_red[0] + s_red[1] + s_red[2] + s_red[3] + attn1_b[0];

    for (int l = wv; l < LL; l += 4) {
        float q = 0.f;
        for (int j = lane; j < HH; j += 64) q += s_enc[l * HH + j] * attn1_w[HH + j];
        #pragma unroll
        for (int o = 32; o; o >>= 1) q += __shfl_xor(q, o);
        if (lane == 0) s_scores[l] = q + semb;
    }
    __syncthreads();

    float mx = -3.4e38f;
    #pragma unroll
    for (int l = 0; l < LL; l++) mx = fmaxf(mx, s_scores[l]);
    float aw[LL], sum = 0.f;
    #pragma unroll
    for (int l = 0; l < LL; l++) { aw[l] = __expf(s_scores[l] - mx); sum += aw[l]; }
    const float inv = 1.f / sum;
    #pragma unroll
    for (int l = 0; l < LL; l++) aw[l] *= inv;

    if (tid < LL) attn_out[tid * BB + b] = aw[tid];

    for (int j = tid; j < HH; j += 256) {
        float c = 0.f;
        #pragma unroll
        for (int l = 0; l < LL; l++) c += aw[l] * s_enc[l * HH + j];
        cat_out[(size_t)b * (2 * HH) + j] = f2bf(embr[j]);
        cat_out[(size_t)b * (2 * HH) + HH + j] = f2bf(c);
    }
}

// ---------------------------------------------------------------------------
// bf16 NT GEMM, counted-vmcnt pipeline (r7/r11, replay-proven).
// GATES=1: blockIdx.z picks second operand set.
// ---------------------------------------------------------------------------
template<int TM, int TN, int OUT, int GATES>
__global__ __launch_bounds__(256)
void gemm_nt(const bf16* __restrict__ A, const bf16* __restrict__ B,
             const float* __restrict__ bias, void* __restrict__ Cout,
             const bf16* __restrict__ A2, const bf16* __restrict__ B2,
             const float* __restrict__ bias2, void* __restrict__ C2,
             const int K, const int N) {
    constexpr int FM = TM / 32, FN = TN / 32;
    __shared__ bf16 As[2][TM * 64];
    __shared__ bf16 Bs[2][TN * 64];

    if (GATES && blockIdx.z == 1) { A = A2; B = B2; bias = bias2; Cout = C2; }

    const int tid = threadIdx.x;
    const int lane = tid & 63, wave = tid >> 6;
    const int wm = wave >> 1, wn = wave & 1;
    const int rlo = lane & 15, khi = lane >> 4;
    const int m0 = blockIdx.y * TM, n0 = blockIdx.x * TN;

    f32x4 acc[FM][FN] = {};
    constexpr int IA = TM / 32, IB = TN / 32;

    auto stage = [&](int k0, int buf) {
        #pragma unroll
        for (int i = 0; i < IA; i++) {
            const int p = (i * 256 + tid) * 16;
            const int row = p >> 7;
            const int qs = (p & 127) ^ ((row & 7) << 4);
            gld_lds16(A + (size_t)(m0 + row) * K + k0 + (qs >> 1),
                      &As[buf][0] + i * 2048 + wave * 512);
        }
        #pragma unroll
        for (int i = 0; i < IB; i++) {
            const int p = (i * 256 + tid) * 16;
            const int row = p >> 7;
            const int qs = (p & 127) ^ ((row & 7) << 4);
            gld_lds16(B + (size_t)(n0 + row) * K + k0 + (qs >> 1),
                      &Bs[buf][0] + i * 2048 + wave * 512);
        }
    };

    auto compute = [&](int buf) {
        #pragma unroll
        for (int ks = 0; ks < 2; ks++) {
            bf16x8 af[FM], bfr[FN];
            #pragma unroll
            for (int m = 0; m < FM; m++) {
                const int r = wm * (TM / 2) + m * 16 + rlo;
                const int sw = (ks * 64 + khi * 16) ^ ((r & 7) << 4);
                af[m] = *(const bf16x8*)((const char*)&As[buf][0] + r * 128 + sw);
            }
            #pragma unroll
            for (int n = 0; n < FN; n++) {
                const int r = wn * (TN / 2) + n * 16 + rlo;
                const int sw = (ks * 64 + khi * 16) ^ ((r & 7) << 4);
                bfr[n] = *(const bf16x8*)((const char*)&Bs[buf][0] + r * 128 + sw);
            }
            #pragma unroll
            for (int m = 0; m < FM; m++)
                #pragma unroll
                for (int n = 0; n < FN; n++)
                    acc[m][n] = __builtin_amdgcn_mfma_f32_16x16x32_bf16(af[m], bfr[n], acc[m][n], 0, 0, 0);
        }
    };

    const int NT = K >> 6;
    stage(0, 0);
    stage(64, 1);

    for (int kt = 0; kt < NT; kt += 2) {
        {
            const int t = kt;
            if (t + 1 < NT) { VMCNT(4); } else { VMCNT(0); }
            SCHED0; SBAR; SCHED0;
            compute(0);
            SCHED0; SBAR; SCHED0;
            if (t + 2 < NT) stage((t + 2) << 6, 0);
        }
        {
            const int t = kt + 1;
            if (t + 1 < NT) { VMCNT(4); } else { VMCNT(0); }
            SCHED0; SBAR; SCHED0;
            compute(1);
            SCHED0; SBAR; SCHED0;
            if (t + 2 < NT) stage((t + 2) << 6, 1);
        }
    }

    #pragma unroll
    for (int m = 0; m < FM; m++) {
        const int gr = m0 + wm * (TM / 2) + m * 16 + khi * 4;
        #pragma unroll
        for (int n = 0; n < FN; n++) {
            const int gc = n0 + wn * (TN / 2) + n * 16 + rlo;
            const float bv = bias[gc];
            #pragma unroll
            for (int j = 0; j < 4; j++) {
                float v = acc[m][n][j] + bv;
                if (OUT == 1) {
                    v = fmaxf(v, 0.f);
                    ((unsigned short*)Cout)[(size_t)(gr + j) * N + gc] = f2bf(v);
                } else {
                    ((float*)Cout)[(size_t)(gr + j) * N + gc] = v;
                }
            }
        }
    }
}

// ---------------------------------------------------------------------------
// Logits GEMM (r11-proven): B from packed 16-KB ktiles, counted VMCNT(8).
// CB=0: C f32 -> d_out. CB=1: C bf16 -> dedicated Cb (lsm converts).
// ---------------------------------------------------------------------------
template<int CB>
__global__ __launch_bounds__(256, 2)
void gemm_out(const bf16* __restrict__ A, const bf16* __restrict__ Bp,
              const float* __restrict__ bias, float* __restrict__ C,
              unsigned short* __restrict__ Cb,
              float* __restrict__ pmax, float* __restrict__ psum) {
    constexpr int K = HH, N = VV;
    __shared__ bf16 As[2][128 * 64];
    __shared__ bf16 Bs[2][128 * 64];
    __shared__ float sPm[2][128], sPs[2][128];

    const int tid = threadIdx.x;
    const int lane = tid & 63, wave = tid >> 6;
    const int wm = wave >> 1, wn = wave & 1;
    const int rlo = lane & 15, khi = lane >> 4;

    constexpr int gridN = 250;
    constexpr int nFull = (gridN >> 3) << 5;    // 992
    const int bidx = blockIdx.x;
    int g, jm;
    if (bidx < nFull) { const int s = bidx >> 5, rem = bidx & 31; jm = rem >> 3; g = s * 8 + (rem & 7); }
    else { const int rem = bidx - nFull; constexpr int gleft = gridN & 7; g = (gridN & ~7) + rem % gleft; jm = rem / gleft; }
    const int n0 = g * 128, m0 = jm * 128;

    const char* pb = (const char*)(Bp + (size_t)g * 131072);   // panel base

    f32x4 acc[4][4] = {};

    auto stage = [&](int k0, int buf) {
        #pragma unroll
        for (int i = 0; i < 4; i++) {          // A: 128x64 bf16, pre-swizzled src
            const int p = (i * 256 + tid) * 16;
            const int row = p >> 7;
            const int qs = (p & 127) ^ ((row & 7) << 4);
            gld_lds16(A + (size_t)(m0 + row) * K + k0 + (qs >> 1),
                      &As[buf][0] + i * 2048 + wave * 512);
        }
        #pragma unroll
        for (int i = 0; i < 4; i++) {          // B: 16 KB packed ktile, pre-swizzled
            const int p = (i * 256 + tid) * 16;
            const int row = p >> 7;
            const int qs = (p & 127) ^ ((row & 7) << 4);
            gld_lds16(pb + (size_t)(k0 >> 6) * 16384 + row * 128 + qs,
                      &Bs[buf][0] + i * 2048 + wave * 512);
        }
    };

    auto compute = [&](int buf) {
        #pragma unroll
        for (int ks = 0; ks < 2; ks++) {
            bf16x8 af[4], bfr[4];
            #pragma unroll
            for (int m = 0; m < 4; m++) {
                const int r = wm * 64 + m * 16 + rlo;
                const int sw = (ks * 64 + khi * 16) ^ ((r & 7) << 4);
                af[m] = *(const bf16x8*)((const char*)&As[buf][0] + r * 128 + sw);
            }
            #pragma unroll
            for (int n = 0; n < 4; n++) {
                const int r = wn * 64 + n * 16 + rlo;
                const int sw = (ks * 64 + khi * 16) ^ ((r & 7) << 4);
                bfr[n] = *(const bf16x8*)((const char*)&Bs[buf][0] + r * 128 + sw);
            }
            #pragma unroll
            for (int m = 0; m < 4; m++)
                #pragma unroll
                for (int n = 0; n < 4; n++)
                    acc[m][n] = __builtin_amdgcn_mfma_f32_16x16x32_bf16(af[m], bfr[n], acc[m][n], 0, 0, 0);
        }
    };

    constexpr int NT = K >> 6;      // 16
    stage(0, 0);
    stage(64, 1);

    for (int kt = 0; kt < NT; kt += 2) {
        {
            const int t = kt;
            if (t + 1 < NT) { VMCNT(8); } else { VMCNT(0); }
            SCHED0; SBAR; SCHED0;
            compute(0);
            SCHED0; SBAR; SCHED0;
            if (t + 2 < NT) stage((t + 2) << 6, 0);
        }
        {
            const int t = kt + 1;
            if (t + 1 < NT) { VMCNT(8); } else { VMCNT(0); }
            SCHED0; SBAR; SCHED0;
            compute(1);
            SCHED0; SBAR; SCHED0;
            if (t + 2 < NT) stage((t + 2) << 6, 1);
        }
    }

    // epilogue: store C, per-row (max,sumexp) partials over 128 cols
    float bvn[4];
    #pragma unroll
    for (int n = 0; n < 4; n++) bvn[n] = bias[n0 + wn * 64 + n * 16 + rlo];

    #pragma unroll
    for (int m = 0; m < 4; m++) {
        const int rbase = wm * 64 + m * 16 + khi * 4;
        #pragma unroll
        for (int j = 0; j < 4; j++) {
            const int gr = m0 + rbase + j;
            float v[4];
            float lm = -3.4e38f;
            #pragma unroll
            for (int n = 0; n < 4; n++) {
                v[n] = acc[m][n][j] + bvn[n];
                const size_t ci = (size_t)gr * N + n0 + wn * 64 + n * 16 + rlo;
                if (CB) Cb[ci] = f2bf(v[n]); else C[ci] = v[n];
                lm = fmaxf(lm, v[n]);
            }
            #pragma unroll
            for (int o = 8; o; o >>= 1) lm = fmaxf(lm, __shfl_xor(lm, o));
            float ls = 0.f;
            #pragma unroll
            for (int n = 0; n < 4; n++) ls += __expf(v[n] - lm);
            #pragma unroll
            for (int o = 8; o; o >>= 1) ls += __shfl_xor(ls, o);
            if (rlo == 0) { sPm[wn][rbase + j] = lm; sPs[wn][rbase + j] = ls; }
        }
    }
    __syncthreads();
    if (tid < 128) {
        const float ma = sPm[0][tid], mb = sPm[1][tid];
        const float M = fmaxf(ma, mb);
        const float S = sPs[0][tid] * __expf(ma - M) + sPs[1][tid] * __expf(mb - M);
        pmax[(size_t)(m0 + tid) * 256 + g] = M;
        psum[(size_t)(m0 + tid) * 256 + g] = S;
    }
}

// ---------------------------------------------------------------------------
// GRU gates (x4 vectorized); writes h_new f32 (output) + bf16 (A operand)
// ---------------------------------------------------------------------------
__global__ __launch_bounds__(256)
void gru_kernel(const float* __restrict__ gi, const float* __restrict__ gh,
                const float* __restrict__ h, float* __restrict__ hnew,
                unsigned short* __restrict__ hnew_bf) {
    const int i = blockIdx.x * 256 + threadIdx.x;        // x4 elems
    const int e = i * 4;
    const int b = e >> 10, j = e & (HH - 1);
    const size_t o = ((size_t)b * 3 * HH + j) / 4;       // f32x4 units
    const f32x4 ir = ((const f32x4*)gi)[o],          iz = ((const f32x4*)gi)[o + HH / 4],
                in_ = ((const f32x4*)gi)[o + 2 * HH / 4];
    const f32x4 hr = ((const f32x4*)gh)[o],          hz = ((const f32x4*)gh)[o + HH / 4],
                hn = ((const f32x4*)gh)[o + 2 * HH / 4];
    const f32x4 hv = ((const f32x4*)h)[i];
    f32x4 out;
    ushort4 ob;
    #pragma unroll
    for (int c = 0; c < 4; c++) {
        const float r = 1.f / (1.f + __expf(-(ir[c] + hr[c])));
        const float z = 1.f / (1.f + __expf(-(iz[c] + hz[c])));
        const float n = tanhf(in_[c] + r * hn[c]);
        const float v = (1.f - z) * n + z * hv[c];
        out[c] = v;
        ((unsigned short*)&ob)[c] = f2bf(v);
    }
    ((f32x4*)hnew)[i] = out;
    ((ushort4*)hnew_bf)[i] = ob;
}

// ---------------------------------------------------------------------------
// log-softmax finalize. CB=0: in-place on f32 logits. CB=1: read bf16 Cb,
// write f32 logits (single C read at half width).
// ---------------------------------------------------------------------------
template<int CB>
__global__ __launch_bounds__(512)
void lsm_final(const float* __restrict__ pmax, const float* __restrict__ psum,
               const unsigned short* __restrict__ Cb, float* __restrict__ logits) {
    const int b = blockIdx.x, tid = threadIdx.x;
    const int lane = tid & 63, wv = tid >> 6;
    __shared__ float sm[8], ss[8];

    float m = -3.4e38f, s = 0.f;
    if (tid < 250) { m = pmax[(size_t)b * 256 + tid]; s = psum[(size_t)b * 256 + tid]; }
    #pragma unroll
    for (int o = 32; o; o >>= 1) {
        const float mo = __shfl_xor(m, o), so = __shfl_xor(s, o);
        const float nm = fmaxf(m, mo);
        s = s * __expf(m - nm) + so * __expf(mo - nm);
        m = nm;
    }
    if (lane == 0) { sm[wv] = m; ss[wv] = s; }
    __syncthreads();
    float M = sm[0], S;
    #pragma unroll
    for (int w = 1; w < 8; w++) M = fmaxf(M, sm[w]);
    S = ss[0] * __expf(sm[0] - M);
    #pragma unroll
    for (int w = 1; w < 8; w++) S += ss[w] * __expf(sm[w] - M);
    const float lse = M + __logf(S);

    float* row = logits + (size_t)b * VV;
    if (CB) {
        const unsigned short* rowc = Cb + (size_t)b * VV;
        for (int j = tid; j < VV / 8; j += 512) {
            const ushort4 u0 = ((const ushort4*)rowc)[2 * j];
            const ushort4 u1 = ((const ushort4*)rowc)[2 * j + 1];
            f32x4 v0, v1;
            v0[0] = bf2f(u0.x) - lse; v0[1] = bf2f(u0.y) - lse;
            v0[2] = bf2f(u0.z) - lse; v0[3] = bf2f(u0.w) - lse;
            v1[0] = bf2f(u1.x) - lse; v1[1] = bf2f(u1.y) - lse;
            v1[2] = bf2f(u1.z) - lse; v1[3] = bf2f(u1.w) - lse;
            ((f32x4*)row)[2 * j] = v0;
            ((f32x4*)row)[2 * j + 1] = v1;
        }
    } else {
        for (int j = tid; j < VV / 4; j += 512) {
            f32x4 v = ((const f32x4*)row)[j];
            v[0] -= lse; v[1] -= lse; v[2] -= lse; v[3] -= lse;
            ((f32x4*)row)[j] = v;
        }
    }
}

// ---------------------------------------------------------------------------
extern "C" void kernel_launch(void* const* d_in, const int* in_sizes, int n_in,
                              void* d_out, int out_size, void* d_ws, size_t ws_size,
                              hipStream_t stream) {
    const int*   ids       = (const int*)d_in[0];
    const float* hidden    = (const float*)d_in[1];
    const float* enc       = (const float*)d_in[2];
    const float* embedding = (const float*)d_in[4];
    const float* attn1_w   = (const float*)d_in[5];
    const float* attn1_b   = (const float*)d_in[6];
    const float* combine_w = (const float*)d_in[7];
    const float* combine_b = (const float*)d_in[8];
    const float* w_ih      = (const float*)d_in[9];
    const float* w_hh      = (const float*)d_in[10];
    const float* b_ih      = (const float*)d_in[11];
    const float* b_hh      = (const float*)d_in[12];
    const float* out_w     = (const float*)d_in[13];
    const float* out_b     = (const float*)d_in[14];

    float* out_lsm = (float*)d_out;                  // [B,V]
    float* out_h   = out_lsm + (size_t)BB * VV;      // [1,B,H]
    float* out_aw  = out_h + (size_t)BB * HH;        // [L,B,1]

    // ws layout: each buffer has exactly one writer kernel; no overlays.
    char* w = (char*)d_ws;
    unsigned short* packed   = (unsigned short*)w;   w += (size_t)VV * HH * 2;
    unsigned short* w_ih_bf  = (unsigned short*)w;   w += (size_t)3 * HH * HH * 2;
    unsigned short* w_hh_bf  = (unsigned short*)w;   w += (size_t)3 * HH * HH * 2;
    unsigned short* w_cb_bf  = (unsigned short*)w;   w += (size_t)2 * HH * HH * 2;
    unsigned short* cat_bf   = (unsigned short*)w;   w += (size_t)BB * 2 * HH * 2;
    unsigned short* x_bf     = (unsigned short*)w;   w += (size_t)BB * HH * 2;
    unsigned short* hid_bf   = (unsigned short*)w;   w += (size_t)BB * HH * 2;
    unsigned short* hnew_bf  = (unsigned short*)w;   w += (size_t)BB * HH * 2;
    float* gi   = (float*)w;                         w += (size_t)BB * 3 * HH * 4;
    float* gh   = (float*)w;                         w += (size_t)BB * 3 * HH * 4;
    float* pmax = (float*)w;                         w += (size_t)BB * 256 * 4;
    float* psum = (float*)w;                         w += (size_t)BB * 256 * 4;
    unsigned short* Cb = (unsigned short*)w;         // optional, 32.77 MB, single writer
    const size_t needed_cb = (size_t)(w - (char*)d_ws) + (size_t)BB * VV * 2;
    const bool use_cb = ws_size >= needed_cb;        // deterministic per deployment

    // 1) fused prologue: pack out_w + cvt weights/hidden + attention
    prologue<<<NPACKB + NCVTB + BB, 256, 0, stream>>>(
        out_w, packed, w_ih, w_ih_bf, w_hh, w_hh_bf, combine_w, w_cb_bf,
        hidden, hid_bf, ids, enc, embedding, attn1_w, attn1_b, out_aw, cat_bf);

    // 2) x = relu(cat @ combine_w^T + b)   M=512 N=1024 K=2048 -> bf16
    gemm_nt<64, 64, 1, 0><<<dim3(HH / 64, BB / 64), 256, 0, stream>>>(
        (const bf16*)cat_bf, (const bf16*)w_cb_bf, combine_b, x_bf,
        nullptr, nullptr, nullptr, nullptr, 2 * HH, HH);

    // 3) z=0: gh = hidden @ w_hh^T ; z=1: gi = x @ w_ih^T   M=512 N=3072 K=1024
    gemm_nt<64, 64, 0, 1><<<dim3(3 * HH / 64, BB / 64, 2), 256, 0, stream>>>(
        (const bf16*)hid_bf, (const bf16*)w_hh_bf, b_hh, gh,
        (const bf16*)x_bf, (const bf16*)w_ih_bf, b_ih, gi, HH, 3 * HH);

    // 4) GRU gates
    gru_kernel<<<(BB * HH / 4) / 256, 256, 0, stream>>>(gi, gh, hidden, out_h, hnew_bf);

    // 5) logits + lsm partials; 6) lsm finalize
    if (use_cb) {
        gemm_out<1><<<1000, 256, 0, stream>>>(
            (const bf16*)hnew_bf, (const bf16*)packed, out_b, nullptr, Cb, pmax, psum);
        lsm_final<1><<<BB, 512, 0, stream>>>(pmax, psum, Cb, out_lsm);
    } else {
        gemm_out<0><<<1000, 256, 0, stream>>>(
            (const bf16*)hnew_bf, (const bf16*)packed, out_b, out_lsm, nullptr, pmax, psum);
        lsm_final<0><<<BB, 512, 0, stream>>>(pmax, psum, nullptr, out_lsm);
    }
}